// Round 3
// baseline (120.219 us; speedup 1.0000x reference)
//
#include <hip/hip_runtime.h>

#define NHEAD 16
#define TDIM 2048
#define SDIM 2048
#define KMAX 4

#define S4    (SDIM / 4)            // 512 float4 per row
#define HEAD4 (TDIM * S4)           // 1048576 float4 per head (power of 2)
#define COPY4 ((TDIM - 1) * S4)     // float4 per head excluding last row
#define N4    (NHEAD * HEAD4)       // 16777216 float4 total
#define NBLK  2048                  // exactly 8192 waves = chip capacity
#define BLKSZ 256
#define GSTRIDE (NBLK * BLKSZ)      // 524288 float4 per sweep

// Single fused kernel, exactly-resident grid (2048 blocks x 4 waves = 8192):
//  - every block copies a fixed 32-iteration float4 share, skipping each
//    head's last row (power-of-2 head stride -> mask compare, no division).
//  - block NBLK-1 additionally runs the decider (argmax/vote/merge) and
//    writes the 16 last rows. It reads only `in`, so no ordering needed;
//    its extra ~0.5 MB of work hides entirely under the ~100 us bulk copy.
__global__ void __launch_bounds__(BLKSZ, 8)
fused_policy_kernel(const float4* __restrict__ in, float4* __restrict__ out) {
    const int tid = threadIdx.x;
    const int b   = blockIdx.x;

    // ---- bulk copy share (all blocks, fixed trip count, unroll x4 ILP) ----
    {
        const unsigned i0 = (unsigned)b * BLKSZ + tid;
        #pragma unroll 4
        for (int k = 0; k < 32; ++k) {
            const unsigned i = i0 + (unsigned)k * GSTRIDE;
            if ((i & (HEAD4 - 1)) < COPY4) {
                out[i] = in[i];
            }
        }
    }
    if (b != NBLK - 1) return;

    // ---- decider (block NBLK-1 only): 256 threads, 16 per head ----
    __shared__ int s_cand[NHEAD];
    __shared__ int s_replace[NHEAD];
    __shared__ int s_sampled;

    const int head = tid >> 4;
    const int l16  = tid & 15;

    const float4* row = in + (size_t)head * HEAD4 + COPY4;  // head's last row

    // per-head argmax, first-occurrence tie-break (matches jnp.argmax)
    float best = -1.0f;           // inputs are uniform [0,1)
    int   bidx = 1 << 30;
    for (int f = l16; f < S4; f += 16) {
        float4 v = row[f];
        const int e = f * 4;
        if (v.x > best) { best = v.x; bidx = e + 0; }
        if (v.y > best) { best = v.y; bidx = e + 1; }
        if (v.z > best) { best = v.z; bidx = e + 2; }
        if (v.w > best) { best = v.w; bidx = e + 3; }
    }
    #pragma unroll
    for (int off = 8; off > 0; off >>= 1) {
        float ov = __shfl_down(best, off, 16);
        int   oi = __shfl_down(bidx, off, 16);
        if (ov > best || (ov == best && oi < bidx)) { best = ov; bidx = oi; }
    }
    if (l16 == 0) s_cand[head] = bidx;
    __syncthreads();

    if (tid == 0) {
        int cnt[NHEAD];
        int maxv = 0;
        for (int h = 0; h < NHEAD; ++h) {
            int c = 0;
            for (int g = 0; g < NHEAD; ++g) c += (s_cand[g] == s_cand[h]);
            cnt[h] = c;
            if (c > maxv) maxv = c;
        }
        int sampled = 0;
        for (int h = NHEAD - 1; h >= 0; --h)
            if (cnt[h] == maxv) sampled = h;          // first head with mask set
        const bool merge = (maxv <= KMAX);
        for (int h = 0; h < NHEAD; ++h)
            s_replace[h] = (merge && cnt[h] == maxv) ? 1 : 0;
        s_sampled = sampled;
    }
    __syncthreads();

    const int sampled = s_sampled;

    // rewrite the 16 last rows (vectorized)
    for (int idx = tid; idx < NHEAD * S4; idx += BLKSZ) {
        const int h = idx >> 9;          // / S4
        const int f = idx & (S4 - 1);    // % S4
        const int src_h = s_replace[h] ? sampled : h;
        out[(size_t)h * HEAD4 + COPY4 + f] =
            in[(size_t)src_h * HEAD4 + COPY4 + f];
    }
}

extern "C" void kernel_launch(void* const* d_in, const int* in_sizes, int n_in,
                              void* d_out, int out_size, void* d_ws, size_t ws_size,
                              hipStream_t stream) {
    const float* in = (const float*)d_in[0];
    float* out = (float*)d_out;

    fused_policy_kernel<<<NBLK, BLKSZ, 0, stream>>>(
        (const float4*)in, (float4*)out);
}

// Round 4
// 107.742 us; speedup vs baseline: 1.1158x; 1.1158x over previous
//
#include <hip/hip_runtime.h>

#define NHEAD 16
#define TDIM 2048
#define SDIM 2048
#define KMAX 4

#define S4    (SDIM / 4)            // 512 float4 per row
#define HEAD4 (TDIM * S4)           // 1048576 float4 per head (power of 2)
#define COPY4 ((TDIM - 1) * S4)     // float4 per head excluding last row
#define N4    (NHEAD * HEAD4)       // 16777216 float4 total
#define NBLK  2048                  // exactly 8192 waves = chip capacity
#define BLKSZ 256
#define CSTRIDE ((NBLK - 1) * BLKSZ)  // copy stride: 2047 copy blocks

// Single fused kernel, exactly-resident grid (2048 blocks x 4 waves = 8192):
//  - block 0: PURE decider (argmax/vote/merge + write the 16 last rows).
//    No copy share -> it starts at t=0 and its ~10us hides fully under the
//    bulk copy. It reads only `in` and writes only the last rows, which the
//    copy blocks skip -> no ordering needed.
//  - blocks 1..2047: grid-stride float4 copy of everything EXCEPT each
//    head's last row (power-of-2 head stride -> mask compare, no division).
__global__ void __launch_bounds__(BLKSZ, 8)
fused_policy_kernel(const float4* __restrict__ in, float4* __restrict__ out) {
    const int tid = threadIdx.x;
    const int b   = blockIdx.x;

    if (b != 0) {
        // ---- bulk copy (blocks 1..2047) ----
        unsigned i = (unsigned)(b - 1) * BLKSZ + tid;
        #pragma unroll 4
        for (; i < N4; i += CSTRIDE) {
            if ((i & (HEAD4 - 1)) < COPY4) {
                out[i] = in[i];
            }
        }
        return;
    }

    // ---- decider (block 0 only): 256 threads, 16 per head ----
    __shared__ int s_cand[NHEAD];
    __shared__ int s_replace[NHEAD];
    __shared__ int s_sampled;

    const int head = tid >> 4;
    const int l16  = tid & 15;

    const float4* row = in + (size_t)head * HEAD4 + COPY4;  // head's last row

    // per-head argmax, first-occurrence tie-break (matches jnp.argmax)
    float best = -1.0f;           // inputs are uniform [0,1)
    int   bidx = 1 << 30;
    for (int f = l16; f < S4; f += 16) {
        float4 v = row[f];
        const int e = f * 4;
        if (v.x > best) { best = v.x; bidx = e + 0; }
        if (v.y > best) { best = v.y; bidx = e + 1; }
        if (v.z > best) { best = v.z; bidx = e + 2; }
        if (v.w > best) { best = v.w; bidx = e + 3; }
    }
    #pragma unroll
    for (int off = 8; off > 0; off >>= 1) {
        float ov = __shfl_down(best, off, 16);
        int   oi = __shfl_down(bidx, off, 16);
        if (ov > best || (ov == best && oi < bidx)) { best = ov; bidx = oi; }
    }
    if (l16 == 0) s_cand[head] = bidx;
    __syncthreads();

    if (tid == 0) {
        int cnt[NHEAD];
        int maxv = 0;
        for (int h = 0; h < NHEAD; ++h) {
            int c = 0;
            for (int g = 0; g < NHEAD; ++g) c += (s_cand[g] == s_cand[h]);
            cnt[h] = c;
            if (c > maxv) maxv = c;
        }
        int sampled = 0;
        for (int h = NHEAD - 1; h >= 0; --h)
            if (cnt[h] == maxv) sampled = h;          // first head with mask set
        const bool merge = (maxv <= KMAX);
        for (int h = 0; h < NHEAD; ++h)
            s_replace[h] = (merge && cnt[h] == maxv) ? 1 : 0;
        s_sampled = sampled;
    }
    __syncthreads();

    const int sampled = s_sampled;

    // rewrite the 16 last rows (vectorized)
    for (int idx = tid; idx < NHEAD * S4; idx += BLKSZ) {
        const int h = idx >> 9;          // / S4
        const int f = idx & (S4 - 1);    // % S4
        const int src_h = s_replace[h] ? sampled : h;
        out[(size_t)h * HEAD4 + COPY4 + f] =
            in[(size_t)src_h * HEAD4 + COPY4 + f];
    }
}

extern "C" void kernel_launch(void* const* d_in, const int* in_sizes, int n_in,
                              void* d_out, int out_size, void* d_ws, size_t ws_size,
                              hipStream_t stream) {
    const float* in = (const float*)d_in[0];
    float* out = (float*)d_out;

    fused_policy_kernel<<<NBLK, BLKSZ, 0, stream>>>(
        (const float4*)in, (float4*)out);
}